// Round 8
// baseline (254.558 us; speedup 1.0000x reference)
//
#include <hip/hip_runtime.h>

#define T_LEN 2048
#define BSZ 2
#define EMB 1024
#define NHEAD 16
#define HDIM 64
#define QK_LD 2048   // q,k packed [T*B, 2E]

// q-scale folded with log2(e): scores come out pre-multiplied so that
// exp(s) == exp2(s') exactly; flash/avg_w use exp2f (v_exp_f32 IS 2^x on
// AMD). 0.18033688 = 64^-0.5 * log2(e).
#define QSCALE_LOG2E 0.18033688011112042f
#define EXP2F(x) exp2f(x)

typedef __attribute__((ext_vector_type(8))) short short8v;   // 8 bf16 (4 VGPRs)
typedef __attribute__((ext_vector_type(4))) short short4v;   // 4 bf16 (2 VGPRs)
typedef __attribute__((ext_vector_type(4))) float floatx4;   // MFMA C/D

__device__ __forceinline__ short f2bf(float f) {
    unsigned u = __float_as_uint(f);
    u += 0x7fffu + ((u >> 16) & 1u);   // RNE
    return (short)(u >> 16);
}

// 4x f32 -> 4x bf16 by truncation (P values are in (0,1]; <=1 ULP bias on
// the PV numerator only -- threshold headroom 3.8x). 1 VALU/value vs 5 RNE.
__device__ __forceinline__ short4v pack_bf16x4(float a, float b, float c, float d) {
    short4v r;
    r[0] = (short)(__float_as_uint(a) >> 16);
    r[1] = (short)(__float_as_uint(b) >> 16);
    r[2] = (short)(__float_as_uint(c) >> 16);
    r[3] = (short)(__float_as_uint(d) >> 16);
    return r;
}

// 16x16x16 bf16 MFMA (K=16): carried-forward instruction on gfx950.
#if __has_builtin(__builtin_amdgcn_mfma_f32_16x16x16bf16_1k)
#define MFMA16(a, b, c) __builtin_amdgcn_mfma_f32_16x16x16bf16_1k(a, b, c, 0, 0, 0)
#else
__device__ __forceinline__ floatx4 mfma16_asm(short4v a, short4v b, floatx4 c) {
    floatx4 d;
    asm("v_mfma_f32_16x16x16_bf16 %0, %1, %2, %3" : "=v"(d) : "v"(a), "v"(b), "v"(c));
    return d;
}
#define MFMA16(a, b, c) mfma16_asm(a, b, c)
#endif

// async global->LDS, 16B per lane; LDS dest is wave-uniform base + lane*16.
__device__ __forceinline__ void async16(const short* g, short* l) {
    __builtin_amdgcn_global_load_lds(
        (const __attribute__((address_space(1))) void*)g,
        (__attribute__((address_space(3))) void*)l, 16, 0, 0);
}

// ---------------------------------------------------------------------------
__global__ __launch_bounds__(256) void f32_to_bf16_k(const float* __restrict__ src,
                                                     short* __restrict__ dst, int n) {
    int i = (blockIdx.x * 256 + threadIdx.x) * 4;
    if (i >= n) return;
    float4 v = *(const float4*)(src + i);
    short4 o = make_short4(f2bf(v.x), f2bf(v.y), f2bf(v.z), f2bf(v.w));
    *(short4*)(dst + i) = o;
}

// ---------------------------------------------------------------------------
// C = A[M,K]*B[N,K]^T + bias; cols < scale_cols get *QSCALE_LOG2E (q scale
// with log2e fold). bf16 MFMA 16x16x32, 128x128 tile, BK=32, 4 waves.
// Staging: global_load_lds width 16, linear LDS dest + inverse-swizzled
// global source (rule 21). GRID IS (mtile, ntile): linear%8 = mtile%8.
// If vTout != 0, cols >= 2*EMB are written TRANSPOSED to vT[b][e][t].
// ---------------------------------------------------------------------------
__global__ __launch_bounds__(256) void gemm_bf16(const short* __restrict__ A,
        const short* __restrict__ B, const float* __restrict__ bias,
        void* __restrict__ Cout, short* __restrict__ vTout,
        int M, int N, int K, int scale_cols, int out_bf16, int ldC) {
    __shared__ short As[128][32];
    __shared__ short Bs[128][32];
    const int tid = threadIdx.x;
    const int m0 = blockIdx.x * 128, n0 = blockIdx.y * 128;   // x=mtile (XCD locality)
    const int lane = tid & 63, w = tid >> 6;
    const int q = lane >> 4, r = lane & 15;
    const int wr = w >> 1, wc = w & 1;

    const int srow = lane >> 2;                  // 0..15 within chunk
    const int spos = lane & 3;                   // 16B slot within row
    const int rowL = w * 16 + srow;              // chunk w   (rows 0..63)
    const int rowH = 64 + rowL;                  // chunk w+4 (rows 64..127)
    const int csrc = spos ^ ((rowL >> 1) & 3);   // f(rowH) == f(rowL)
    const short* gA0 = A + (size_t)(m0 + rowL) * K + csrc * 8;
    const short* gA1 = A + (size_t)(m0 + rowH) * K + csrc * 8;
    const short* gB0 = B + (size_t)(n0 + rowL) * K + csrc * 8;
    const short* gB1 = B + (size_t)(n0 + rowH) * K + csrc * 8;
    short* lA0 = &As[w * 16][0];                 // wave-uniform LDS bases
    short* lA1 = &As[64 + w * 16][0];
    short* lB0 = &Bs[w * 16][0];
    short* lB1 = &Bs[64 + w * 16][0];

    floatx4 acc[4][4];
    #pragma unroll
    for (int a = 0; a < 4; ++a)
        #pragma unroll
        for (int b2 = 0; b2 < 4; ++b2)
            #pragma unroll
            for (int e = 0; e < 4; ++e) acc[a][b2][e] = 0.f;

    for (int k0 = 0; k0 < K; k0 += 32) {
        __syncthreads();                 // previous iter's ds_reads complete
        async16(gA0 + k0, lA0);
        async16(gA1 + k0, lA1);
        async16(gB0 + k0, lB0);
        async16(gB1 + k0, lB1);
        __syncthreads();                 // vmcnt(0) drain + barrier
        short8v af[4], bfr[4];
        #pragma unroll
        for (int mb = 0; mb < 4; ++mb) {
            int row = wr * 64 + mb * 16 + r;
            af[mb] = *(const short8v*)&As[row][(q ^ ((row >> 1) & 3)) * 8];
        }
        #pragma unroll
        for (int nb = 0; nb < 4; ++nb) {
            int row = wc * 64 + nb * 16 + r;
            bfr[nb] = *(const short8v*)&Bs[row][(q ^ ((row >> 1) & 3)) * 8];
        }
        #pragma unroll
        for (int mb = 0; mb < 4; ++mb)
            #pragma unroll
            for (int nb = 0; nb < 4; ++nb)
                acc[mb][nb] = __builtin_amdgcn_mfma_f32_16x16x32_bf16(af[mb], bfr[nb], acc[mb][nb], 0, 0, 0);
    }

    #pragma unroll
    for (int nb = 0; nb < 4; ++nb) {
        const int col = n0 + wc * 64 + nb * 16 + r;
        const float bi = bias[col];
        const float sc = (col < scale_cols) ? QSCALE_LOG2E : 1.0f;
        if (vTout && col >= 2 * EMB) {
            const int e = col - 2 * EMB;
            #pragma unroll
            for (int mb = 0; mb < 4; ++mb) {
                const int base = m0 + wr * 64 + mb * 16 + q * 4;   // multiple of 4
                float v0 = acc[mb][nb][0] + bi, v1 = acc[mb][nb][1] + bi;
                float v2 = acc[mb][nb][2] + bi, v3 = acc[mb][nb][3] + bi;
                unsigned lo = (unsigned short)f2bf(v0) | ((unsigned)(unsigned short)f2bf(v2) << 16);
                unsigned hi = (unsigned short)f2bf(v1) | ((unsigned)(unsigned short)f2bf(v3) << 16);
                *(unsigned*)&vTout[(size_t)e * T_LEN + (base >> 1)]         = lo;
                *(unsigned*)&vTout[((size_t)EMB + e) * T_LEN + (base >> 1)] = hi;
            }
        } else {
            #pragma unroll
            for (int mb = 0; mb < 4; ++mb)
                #pragma unroll
                for (int i = 0; i < 4; ++i) {
                    const int rowg = m0 + wr * 64 + mb * 16 + q * 4 + i;
                    const float v = (acc[mb][nb][i] + bi) * sc;
                    if (out_bf16) ((short*)Cout)[(size_t)rowg * ldC + col] = f2bf(v);
                    else          ((float*)Cout)[(size_t)rowg * ldC + col] = v;
                }
        }
    }
}

// ---------------------------------------------------------------------------
// Flash causal attention, SWAPPED-QK in-register-P version (R5 structure).
// Scores pre-scaled by log2e (GEMM fold) -> exp2f; P->bf16 by truncation.
// ---------------------------------------------------------------------------
__global__ __launch_bounds__(256) void flash_fwd(const short* __restrict__ qk,
        const short* __restrict__ vT, short* __restrict__ ctx,
        float* __restrict__ Lr) {
    __shared__ __align__(16) short Ks[128][64];   // 2 s-tiles of K; Q pre-loop; O-reduce overlay post-loop
    __shared__ __align__(16) short Vt[64][128];   // V^T [d][2 s-tiles]; O-reduce overlay post-loop
    __shared__ float Lred[4][64];
    const int tid = threadIdx.x;
    const int bh = blockIdx.x;          // XCD locality: linear%8 = bh%8
    const int tt = 31 - blockIdx.y;     // big tiles first
    const int t0 = tt << 6;
    const int b = bh >> 4, h = bh & 15;
    const int lane = tid & 63, w = tid >> 6;
    const int q = lane >> 4, r = lane & 15;
    const int RS = BSZ * QK_LD;

    const short* qbase = qk + (size_t)b * QK_LD + h * HDIM;
    const short* kbase = qbase + EMB;
    const short* vbase = vT + ((size_t)b * EMB + h * HDIM) * T_LEN;

    // async staging geometry (paired rounds), same as verified R4/R5:
    const int krow0 = w * 32 + (lane >> 3);
    const short* kg = kbase + (size_t)krow0 * RS + ((lane & 7) ^ (krow0 & 7)) * 8;
    const int vrow0 = w * 16 + (lane >> 4);
    const short* vg[4];
    #pragma unroll
    for (int j = 0; j < 4; ++j) {
        const int vr = vrow0 + j * 4;
        const int gc = ((lane & 15) & 8) | (((lane & 15) & 7) ^ (vr & 7));
        vg[j] = vbase + (size_t)vr * T_LEN + gc * 8;
    }

    {   // stage Q into Ks (dead until first K staging round)
        const int sr = tid >> 3, c8 = tid & 7;
        *(int4*)&Ks[sr][(c8 ^ (sr & 7)) * 8] =
            *(const int4*)(qbase + (size_t)(t0 + sr) * RS + c8 * 8);
        *(int4*)&Ks[sr + 32][(c8 ^ ((sr + 32) & 7)) * 8] =
            *(const int4*)(qbase + (size_t)(t0 + sr + 32) * RS + c8 * 8);
    }
    __syncthreads();
    short8v qf[4][2];
    #pragma unroll
    for (int mb = 0; mb < 4; ++mb)
        #pragma unroll
        for (int ks = 0; ks < 2; ++ks) {
            int row = mb * 16 + r;
            qf[mb][ks] = *(const short8v*)&Ks[row][((ks * 4 + q) ^ (row & 7)) * 8];
        }

    float l_part[4] = {0.f, 0.f, 0.f, 0.f};
    floatx4 o[4][4];
    #pragma unroll
    for (int mb = 0; mb < 4; ++mb)
        #pragma unroll
        for (int nb = 0; nb < 4; ++nb)
            #pragma unroll
            for (int e = 0; e < 4; ++e) o[mb][nb][e] = 0.f;

    // V read position: global 16B-chunk g = t2*8 + w*2 + (q>>1); LDS chunk
    // holding it = (g&8)|((g&7)^(d&7)), d&7 == r&7; +(q&1)*4 shorts for the
    // 8B half. s covered = t2*64 + w*16 + q*4 + j  (j=0..3 within the b64).
    const int voffbase = (((w * 2 + (q >> 1)) ^ (r & 7)) * 8) + (q & 1) * 4;

    const int ntiles = tt + 1;
    int s2 = 0;
    for (; s2 + 2 <= ntiles; s2 += 2) {   // paired rounds: 128 s per stage
        __syncthreads();                  // prior round's Ks/Vt reads done
        {
            const short* kgr = kg + (size_t)(s2 * 64) * RS;
            #pragma unroll
            for (int j = 0; j < 4; ++j)
                async16(kgr + (size_t)(j * 8) * RS, &Ks[w * 32 + j * 8][0]);
            #pragma unroll
            for (int j = 0; j < 4; ++j)
                async16(vg[j] + s2 * 64, &Vt[w * 16 + j * 4][0]);
        }
        __syncthreads();                  // vmcnt(0) drain + barrier
        #pragma unroll
        for (int t2 = 0; t2 < 2; ++t2) {
            const int krow = t2 * 64 + w * 16 + r;
            const int ksw = krow & 7;
            short8v kf0 = *(const short8v*)&Ks[krow][(q ^ ksw) * 8];
            short8v kf1 = *(const short8v*)&Ks[krow][((4 + q) ^ ksw) * 8];
            short4v vf[4];
            #pragma unroll
            for (int nb = 0; nb < 4; ++nb)
                vf[nb] = *(const short4v*)&Vt[nb * 16 + r][t2 * 64 + voffbase];
            const bool diag = (s2 + t2 == tt);
            #pragma unroll
            for (int mb = 0; mb < 4; ++mb) {
                floatx4 sf;
                #pragma unroll
                for (int e = 0; e < 4; ++e) sf[e] = 0.f;
                sf = __builtin_amdgcn_mfma_f32_16x16x32_bf16(kf0, qf[mb][0], sf, 0, 0, 0);
                sf = __builtin_amdgcn_mfma_f32_16x16x32_bf16(kf1, qf[mb][1], sf, 0, 0, 0);
                const int t_in = mb * 16 + r;
                const int s_in = w * 16 + q * 4;
                float p0 = (diag && (s_in + 0 > t_in)) ? 0.f : EXP2F(sf[0]);
                float p1 = (diag && (s_in + 1 > t_in)) ? 0.f : EXP2F(sf[1]);
                float p2 = (diag && (s_in + 2 > t_in)) ? 0.f : EXP2F(sf[2]);
                float p3 = (diag && (s_in + 3 > t_in)) ? 0.f : EXP2F(sf[3]);
                l_part[mb] += (p0 + p1) + (p2 + p3);
                short4v pa = pack_bf16x4(p0, p1, p2, p3);
                #pragma unroll
                for (int nb = 0; nb < 4; ++nb)
                    o[mb][nb] = MFMA16(pa, vf[nb], o[mb][nb]);
            }
        }
    }
    if (s2 < ntiles) {   // odd tail: single tile s2 == tt (diagonal)
        __syncthreads();
        {   // 64 rows x 8 chunks each (2 int4/thread), read-swizzle-matched
            const int sr = tid >> 2, cb = (tid & 3) * 2;
            const short* kp = kbase + (size_t)(s2 * 64 + sr) * RS;
            const short* vp = vbase + (size_t)sr * T_LEN + s2 * 64;
            #pragma unroll
            for (int u = 0; u < 2; ++u) {
                const int c = cb + u;
                *(int4*)&Ks[sr][(c ^ (sr & 7)) * 8] = *(const int4*)(kp + c * 8);
                *(int4*)&Vt[sr][(c ^ (sr & 7)) * 8] = *(const int4*)(vp + c * 8);
            }
        }
        __syncthreads();
        const int krow = w * 16 + r;
        const int ksw = krow & 7;
        short8v kf0 = *(const short8v*)&Ks[krow][(q ^ ksw) * 8];
        short8v kf1 = *(const short8v*)&Ks[krow][((4 + q) ^ ksw) * 8];
        short4v vf[4];
        #pragma unroll
        for (int nb = 0; nb < 4; ++nb)
            vf[nb] = *(const short4v*)&Vt[nb * 16 + r][voffbase];
        #pragma unroll
        for (int mb = 0; mb < 4; ++mb) {
            floatx4 sf;
            #pragma unroll
            for (int e = 0; e < 4; ++e) sf[e] = 0.f;
            sf = __builtin_amdgcn_mfma_f32_16x16x32_bf16(kf0, qf[mb][0], sf, 0, 0, 0);
            sf = __builtin_amdgcn_mfma_f32_16x16x32_bf16(kf1, qf[mb][1], sf, 0, 0, 0);
            const int t_in = mb * 16 + r;
            const int s_in = w * 16 + q * 4;
            float p0 = (s_in + 0 > t_in) ? 0.f : EXP2F(sf[0]);
            float p1 = (s_in + 1 > t_in) ? 0.f : EXP2F(sf[1]);
            float p2 = (s_in + 2 > t_in) ? 0.f : EXP2F(sf[2]);
            float p3 = (s_in + 3 > t_in) ? 0.f : EXP2F(sf[3]);
            l_part[mb] += (p0 + p1) + (p2 + p3);
            short4v pa = pack_bf16x4(p0, p1, p2, p3);
            #pragma unroll
            for (int nb = 0; nb < 4; ++nb)
                o[mb][nb] = MFMA16(pa, vf[nb], o[mb][nb]);
        }
    }

    // ---- epilogue 1: l reduction. lane (q,r) holds partial for t=mb*16+r
    // summed over its s-stripe; sum over q (xor 16,32), then cross-wave.
    #pragma unroll
    for (int mb = 0; mb < 4; ++mb) {
        float v = l_part[mb];
        v += __shfl_xor(v, 16);
        v += __shfl_xor(v, 32);
        if (q == 0) Lred[w][mb * 16 + r] = v;
    }
    __syncthreads();
    if (tid < 64) {
        float s = Lred[0][tid] + Lred[1][tid] + Lred[2][tid] + Lred[3][tid];
        Lr[(size_t)bh * T_LEN + t0 + tid] = s;
        Lred[0][tid] = 1.0f / s;
    }
    __syncthreads();

    // ---- epilogue 2: cross-wave O reduction via LDS overlay.
    // Waves 0,1 -> Ks region; waves 2,3 -> Vt region; [2][64][20] f32 each
    // (pad 20 keeps float4 alignment + 2-way banks). 4 rounds (one per nb).
    float* OA = (float*)&Ks[0][0];
    float* OB = (float*)&Vt[0][0];
    float* myO = ((w < 2) ? OA : OB) + (size_t)(w & 1) * (64 * 20);
    const int tr = tid >> 2, d4 = (tid & 3) * 4;
    const float inv = Lred[0][tr];
    short* cbase = ctx + ((size_t)(t0 + tr) * BSZ + b) * EMB + h * HDIM + d4;
    #pragma unroll
    for (int nb = 0; nb < 4; ++nb) {
        #pragma unroll
        for (int mb = 0; mb < 4; ++mb)
            #pragma unroll
            for (int i = 0; i < 4; ++i)
                myO[(mb * 16 + q * 4 + i) * 20 + r] = o[mb][nb][i];
        __syncthreads();
        float4 va = *(float4*)&OA[tr * 20 + d4];
        float4 vb = *(float4*)&OA[64 * 20 + tr * 20 + d4];
        float4 vc = *(float4*)&OB[tr * 20 + d4];
        float4 vd = *(float4*)&OB[64 * 20 + tr * 20 + d4];
        float v0 = (va.x + vb.x + vc.x + vd.x) * inv;
        float v1 = (va.y + vb.y + vc.y + vd.y) * inv;
        float v2 = (va.z + vb.z + vc.z + vd.z) * inv;
        float v3 = (va.w + vb.w + vc.w + vd.w) * inv;
        short4 pk = make_short4(f2bf(v0), f2bf(v1), f2bf(v2), f2bf(v3));
        *(short4*)(cbase + nb * 16) = pk;
        if (nb < 3) __syncthreads();
    }
}

// ---------------------------------------------------------------------------
// avg_w[b,t,s] = (1/H) sum_h exp2(qk') / l_h[t]  (scores pre-scaled by
// log2e in the GEMM). 64x64 output tiles, 2 heads per staging round,
// staging via global_load_lds width 16 (verified R4).
// ---------------------------------------------------------------------------
__global__ __launch_bounds__(256) void avg_w_k(const short* __restrict__ qk,
        const float* __restrict__ Lr, float* __restrict__ avg) {
    const int s0 = blockIdx.x * 64, t0 = blockIdx.y * 64, b = blockIdx.z;
    const int tid = threadIdx.x;
    float* outb = avg + (size_t)b * T_LEN * T_LEN;
    if (s0 > t0) {   // fully masked tile: zero-fill (d_out is poisoned)
        const int ty = tid >> 4, tx = tid & 15;
        const float4 z = make_float4(0.f, 0.f, 0.f, 0.f);
        #pragma unroll
        for (int i = 0; i < 4; ++i)
            *(float4*)&outb[(size_t)(t0 + ty * 4 + i) * T_LEN + s0 + tx * 4] = z;
        return;
    }
    __shared__ short Qs[64][128];
    __shared__ short Ks[64][128];
    __shared__ float Lbuf[NHEAD][64];
    const int lane = tid & 63, w = tid >> 6;
    const int q = lane >> 4, r = lane & 15;
    const short* qbase = qk + (size_t)b * QK_LD;
    const int RS = BSZ * QK_LD;

    // pre-inverted denominators: 16 heads x 64 t-rows (published by drain barrier)
    #pragma unroll
    for (int u = 0; u < 4; ++u) {
        const int li = tid * 4 + u;
        const int h = li >> 6, tl = li & 63;
        Lbuf[h][tl] = 0.0625f / Lr[(size_t)(b * NHEAD + h) * T_LEN + t0 + tl];
    }

    // async staging: wave w stages rows [w*16, w*16+16) of Qs and Ks via
    // 4 issues of 4 rows; global source chunk = (c&8)|((c&7)^(row&7)).
    const short* qg[4]; const short* kg[4];
    #pragma unroll
    for (int j = 0; j < 4; ++j) {
        const int row = w * 16 + j * 4 + (lane >> 4);
        const int c = lane & 15;
        const int gc = (c & 8) | ((c & 7) ^ (row & 7));
        qg[j] = qbase + (size_t)(t0 + row) * RS + gc * 8;
        kg[j] = qbase + EMB + (size_t)(s0 + row) * RS + gc * 8;
    }

    floatx4 acc[4];
    #pragma unroll
    for (int nb = 0; nb < 4; ++nb)
        #pragma unroll
        for (int e = 0; e < 4; ++e) acc[nb][e] = 0.f;

    for (int hp = 0; hp < 8; ++hp) {       // head pairs; hp offset = hp*128 shorts
        __syncthreads();                   // prior round's fragment reads done
        #pragma unroll
        for (int j = 0; j < 4; ++j)
            async16(qg[j] + hp * 128, &Qs[w * 16 + j * 4][0]);
        #pragma unroll
        for (int j = 0; j < 4; ++j)
            async16(kg[j] + hp * 128, &Ks[w * 16 + j * 4][0]);
        __syncthreads();                   // vmcnt(0) drain + barrier

        #pragma unroll
        for (int hs = 0; hs < 2; ++hs) {
            const int h = hp * 2 + hs;
            floatx4 sf[4];
            #pragma unroll
            for (int nb = 0; nb < 4; ++nb)
                #pragma unroll
                for (int e = 0; e < 4; ++e) sf[nb][e] = 0.f;
            #pragma unroll
            for (int ks = 0; ks < 2; ++ks) {
                const int qrow = w * 16 + r;
                short8v qfr = *(const short8v*)
                    &Qs[qrow][((hs * 8) | ((ks * 4 + q) ^ (qrow & 7))) * 8];
                #pragma unroll
                for (int nb = 0; nb < 4; ++nb) {
                    const int krow = nb * 16 + r;
                    short8v kfr = *(const short8v*)
                        &Ks[krow][((hs * 8) | ((ks * 4 + q) ^ (krow & 7))) * 8];
                    sf[nb] = __builtin_amdgcn_mfma_f32_16x16x32_bf16(qfr, kfr, sf[nb], 0, 0, 0);
                }
            }
            #pragma unroll
            for (int i = 0; i < 4; ++i) {
                const int tl = w * 16 + q * 4 + i;
                const float inv = Lbuf[h][tl];
                #pragma unroll
                for (int nb = 0; nb < 4; ++nb) {
                    float e = (s0 == t0 && (nb * 16 + r > tl))
                              ? 0.f : EXP2F(sf[nb][i]) * inv;
                    acc[nb][i] += e;
                }
            }
        }
    }

    #pragma unroll
    for (int i = 0; i < 4; ++i) {
        const int t = t0 + w * 16 + q * 4 + i;
        #pragma unroll
        for (int nb = 0; nb < 4; ++nb)
            outb[(size_t)t * T_LEN + s0 + nb * 16 + r] = acc[nb][i];
    }
}

// ---------------------------------------------------------------------------
// Workspace (40.25 MiB, proven-safe layout). query-bf16 ALIASED onto ctxb
// (dead before flash_fwd writes ctx; stream-serial).
// ---------------------------------------------------------------------------
extern "C" void kernel_launch(void* const* d_in, const int* in_sizes, int n_in,
                              void* d_out, int out_size, void* d_ws, size_t ws_size,
                              hipStream_t stream) {
    (void)in_sizes; (void)n_in; (void)out_size; (void)ws_size;
    const float* query = (const float*)d_in[0];
    const float* w_in  = (const float*)d_in[1];
    const float* b_in  = (const float*)d_in[2];
    const float* w_out = (const float*)d_in[3];
    const float* b_out = (const float*)d_in[4];

    float* out = (float*)d_out;                           // [T,B,E] fp32
    float* avg = out + (size_t)T_LEN * BSZ * EMB;         // [B,T,T] fp32

    short* ws     = (short*)d_ws;
    short* wb_in  = ws;                                   // w_in bf16  [3072,1024]  6 MB
    short* wb_out = wb_in  + (size_t)3072 * 1024;         // w_out bf16 [1024,1024]  2 MB
    short* qkb    = wb_out + (size_t)1024 * 1024;         // q,k bf16   [4096,2048] 16 MB
    short* vTb    = qkb    + (size_t)4096 * 2048;         // V^T bf16   [B*E, T]     8 MB
    short* ctxb   = vTb    + (size_t)BSZ * EMB * T_LEN;   // ctx bf16   [4096,1024]  8 MB
    float* Lr     = (float*)(ctxb + (size_t)4096 * 1024); // [B*H, T]              256 KB
    short* qb     = ctxb;                                 // query bf16 alias (dead before flash)

    f32_to_bf16_k<<<4096, 256, 0, stream>>>(query, qb,     4096 * 1024);
    f32_to_bf16_k<<<3072, 256, 0, stream>>>(w_in,  wb_in,  3072 * 1024);
    f32_to_bf16_k<<<1024, 256, 0, stream>>>(w_out, wb_out, 1024 * 1024);

    // QKV projection: q,k -> qkb (q pre-scaled by 0.125*log2e), v -> vTb
    gemm_bf16<<<dim3(32, 24), 256, 0, stream>>>(qb, wb_in, b_in, qkb, vTb,
                                                4096, 3072, 1024, EMB, 1, QK_LD);
    flash_fwd<<<dim3(32, 32), 256, 0, stream>>>(qkb, vTb, ctxb, Lr);
    avg_w_k<<<dim3(32, 32, 2), 256, 0, stream>>>(qkb, Lr, avg);
    gemm_bf16<<<dim3(32, 8), 256, 0, stream>>>(ctxb, wb_out, b_out, out, (short*)0,
                                               4096, 1024, 1024, 0, 0, 1024);
}

// Round 9
// 238.502 us; speedup vs baseline: 1.0673x; 1.0673x over previous
//
#include <hip/hip_runtime.h>

#define T_LEN 2048
#define BSZ 2
#define EMB 1024
#define NHEAD 16
#define HDIM 64
#define QK_LD 2048   // q,k packed [T*B, 2E]

// q-scale folded with log2(e): scores come out pre-multiplied so that
// exp(s) == exp2(s') exactly. 0.18033688 = 64^-0.5 * log2(e).
#define QSCALE_LOG2E 0.18033688011112042f

// Raw hardware exp2: v_exp_f32 IS 2^x (cdna4_isa §3) — the same instruction
// __expf lowers to, minus the ln2 multiply. NOT exp2f (that's the precise
// OCML libcall, ~10 VALU: R8 post-mortem showed it 2x'd avg_w_k).
__device__ __forceinline__ float exp2_hw(float x) {
    float r;
    asm("v_exp_f32 %0, %1" : "=v"(r) : "v"(x));
    return r;
}
#define EXP2F(x) exp2_hw(x)

typedef __attribute__((ext_vector_type(8))) short short8v;   // 8 bf16 (4 VGPRs)
typedef __attribute__((ext_vector_type(4))) short short4v;   // 4 bf16 (2 VGPRs)
typedef __attribute__((ext_vector_type(4))) float floatx4;   // MFMA C/D

__device__ __forceinline__ short f2bf(float f) {
    unsigned u = __float_as_uint(f);
    u += 0x7fffu + ((u >> 16) & 1u);   // RNE
    return (short)(u >> 16);
}

// 4x f32 -> 4x bf16 by truncation (P values are in (0,1]; <=1 ULP bias on
// the PV numerator only -- threshold headroom 3.8x). 1 VALU/value vs 5 RNE.
__device__ __forceinline__ short4v pack_bf16x4(float a, float b, float c, float d) {
    short4v r;
    r[0] = (short)(__float_as_uint(a) >> 16);
    r[1] = (short)(__float_as_uint(b) >> 16);
    r[2] = (short)(__float_as_uint(c) >> 16);
    r[3] = (short)(__float_as_uint(d) >> 16);
    return r;
}

// 16x16x16 bf16 MFMA (K=16): carried-forward instruction on gfx950.
#if __has_builtin(__builtin_amdgcn_mfma_f32_16x16x16bf16_1k)
#define MFMA16(a, b, c) __builtin_amdgcn_mfma_f32_16x16x16bf16_1k(a, b, c, 0, 0, 0)
#else
__device__ __forceinline__ floatx4 mfma16_asm(short4v a, short4v b, floatx4 c) {
    floatx4 d;
    asm("v_mfma_f32_16x16x16_bf16 %0, %1, %2, %3" : "=v"(d) : "v"(a), "v"(b), "v"(c));
    return d;
}
#define MFMA16(a, b, c) mfma16_asm(a, b, c)
#endif

// async global->LDS, 16B per lane; LDS dest is wave-uniform base + lane*16.
__device__ __forceinline__ void async16(const short* g, short* l) {
    __builtin_amdgcn_global_load_lds(
        (const __attribute__((address_space(1))) void*)g,
        (__attribute__((address_space(3))) void*)l, 16, 0, 0);
}

// ---------------------------------------------------------------------------
__global__ __launch_bounds__(256) void f32_to_bf16_k(const float* __restrict__ src,
                                                     short* __restrict__ dst, int n) {
    int i = (blockIdx.x * 256 + threadIdx.x) * 4;
    if (i >= n) return;
    float4 v = *(const float4*)(src + i);
    short4 o = make_short4(f2bf(v.x), f2bf(v.y), f2bf(v.z), f2bf(v.w));
    *(short4*)(dst + i) = o;
}

// ---------------------------------------------------------------------------
// C = A[M,K]*B[N,K]^T + bias; cols < scale_cols get *QSCALE_LOG2E (q scale
// with log2e fold). bf16 MFMA 16x16x32, 128x128 tile, BK=32, 4 waves.
// Staging: global_load_lds width 16, linear LDS dest + inverse-swizzled
// global source (rule 21). GRID IS (mtile, ntile): linear%8 = mtile%8.
// If vTout != 0, cols >= 2*EMB are written TRANSPOSED to vT[b][e][t].
// ---------------------------------------------------------------------------
__global__ __launch_bounds__(256) void gemm_bf16(const short* __restrict__ A,
        const short* __restrict__ B, const float* __restrict__ bias,
        void* __restrict__ Cout, short* __restrict__ vTout,
        int M, int N, int K, int scale_cols, int out_bf16, int ldC) {
    __shared__ short As[128][32];
    __shared__ short Bs[128][32];
    const int tid = threadIdx.x;
    const int m0 = blockIdx.x * 128, n0 = blockIdx.y * 128;   // x=mtile (XCD locality)
    const int lane = tid & 63, w = tid >> 6;
    const int q = lane >> 4, r = lane & 15;
    const int wr = w >> 1, wc = w & 1;

    const int srow = lane >> 2;                  // 0..15 within chunk
    const int spos = lane & 3;                   // 16B slot within row
    const int rowL = w * 16 + srow;              // chunk w   (rows 0..63)
    const int rowH = 64 + rowL;                  // chunk w+4 (rows 64..127)
    const int csrc = spos ^ ((rowL >> 1) & 3);   // f(rowH) == f(rowL)
    const short* gA0 = A + (size_t)(m0 + rowL) * K + csrc * 8;
    const short* gA1 = A + (size_t)(m0 + rowH) * K + csrc * 8;
    const short* gB0 = B + (size_t)(n0 + rowL) * K + csrc * 8;
    const short* gB1 = B + (size_t)(n0 + rowH) * K + csrc * 8;
    short* lA0 = &As[w * 16][0];                 // wave-uniform LDS bases
    short* lA1 = &As[64 + w * 16][0];
    short* lB0 = &Bs[w * 16][0];
    short* lB1 = &Bs[64 + w * 16][0];

    floatx4 acc[4][4];
    #pragma unroll
    for (int a = 0; a < 4; ++a)
        #pragma unroll
        for (int b2 = 0; b2 < 4; ++b2)
            #pragma unroll
            for (int e = 0; e < 4; ++e) acc[a][b2][e] = 0.f;

    for (int k0 = 0; k0 < K; k0 += 32) {
        __syncthreads();                 // previous iter's ds_reads complete
        async16(gA0 + k0, lA0);
        async16(gA1 + k0, lA1);
        async16(gB0 + k0, lB0);
        async16(gB1 + k0, lB1);
        __syncthreads();                 // vmcnt(0) drain + barrier
        short8v af[4], bfr[4];
        #pragma unroll
        for (int mb = 0; mb < 4; ++mb) {
            int row = wr * 64 + mb * 16 + r;
            af[mb] = *(const short8v*)&As[row][(q ^ ((row >> 1) & 3)) * 8];
        }
        #pragma unroll
        for (int nb = 0; nb < 4; ++nb) {
            int row = wc * 64 + nb * 16 + r;
            bfr[nb] = *(const short8v*)&Bs[row][(q ^ ((row >> 1) & 3)) * 8];
        }
        #pragma unroll
        for (int mb = 0; mb < 4; ++mb)
            #pragma unroll
            for (int nb = 0; nb < 4; ++nb)
                acc[mb][nb] = __builtin_amdgcn_mfma_f32_16x16x32_bf16(af[mb], bfr[nb], acc[mb][nb], 0, 0, 0);
    }

    #pragma unroll
    for (int nb = 0; nb < 4; ++nb) {
        const int col = n0 + wc * 64 + nb * 16 + r;
        const float bi = bias[col];
        const float sc = (col < scale_cols) ? QSCALE_LOG2E : 1.0f;
        if (vTout && col >= 2 * EMB) {
            const int e = col - 2 * EMB;
            #pragma unroll
            for (int mb = 0; mb < 4; ++mb) {
                const int base = m0 + wr * 64 + mb * 16 + q * 4;   // multiple of 4
                float v0 = acc[mb][nb][0] + bi, v1 = acc[mb][nb][1] + bi;
                float v2 = acc[mb][nb][2] + bi, v3 = acc[mb][nb][3] + bi;
                unsigned lo = (unsigned short)f2bf(v0) | ((unsigned)(unsigned short)f2bf(v2) << 16);
                unsigned hi = (unsigned short)f2bf(v1) | ((unsigned)(unsigned short)f2bf(v3) << 16);
                *(unsigned*)&vTout[(size_t)e * T_LEN + (base >> 1)]         = lo;
                *(unsigned*)&vTout[((size_t)EMB + e) * T_LEN + (base >> 1)] = hi;
            }
        } else {
            #pragma unroll
            for (int mb = 0; mb < 4; ++mb)
                #pragma unroll
                for (int i = 0; i < 4; ++i) {
                    const int rowg = m0 + wr * 64 + mb * 16 + q * 4 + i;
                    const float v = (acc[mb][nb][i] + bi) * sc;
                    if (out_bf16) ((short*)Cout)[(size_t)rowg * ldC + col] = f2bf(v);
                    else          ((float*)Cout)[(size_t)rowg * ldC + col] = v;
                }
        }
    }
}

// ---------------------------------------------------------------------------
// Flash causal attention, SWAPPED-QK in-register-P version (R5 structure).
// Scores pre-scaled by log2e (GEMM fold) -> v_exp_f32; P->bf16 by truncation.
// ---------------------------------------------------------------------------
__global__ __launch_bounds__(256) void flash_fwd(const short* __restrict__ qk,
        const short* __restrict__ vT, short* __restrict__ ctx,
        float* __restrict__ Lr) {
    __shared__ __align__(16) short Ks[128][64];   // 2 s-tiles of K; Q pre-loop; O-reduce overlay post-loop
    __shared__ __align__(16) short Vt[64][128];   // V^T [d][2 s-tiles]; O-reduce overlay post-loop
    __shared__ float Lred[4][64];
    const int tid = threadIdx.x;
    const int bh = blockIdx.x;          // XCD locality: linear%8 = bh%8
    const int tt = 31 - blockIdx.y;     // big tiles first
    const int t0 = tt << 6;
    const int b = bh >> 4, h = bh & 15;
    const int lane = tid & 63, w = tid >> 6;
    const int q = lane >> 4, r = lane & 15;
    const int RS = BSZ * QK_LD;

    const short* qbase = qk + (size_t)b * QK_LD + h * HDIM;
    const short* kbase = qbase + EMB;
    const short* vbase = vT + ((size_t)b * EMB + h * HDIM) * T_LEN;

    // async staging geometry (paired rounds), same as verified R4/R5:
    const int krow0 = w * 32 + (lane >> 3);
    const short* kg = kbase + (size_t)krow0 * RS + ((lane & 7) ^ (krow0 & 7)) * 8;
    const int vrow0 = w * 16 + (lane >> 4);
    const short* vg[4];
    #pragma unroll
    for (int j = 0; j < 4; ++j) {
        const int vr = vrow0 + j * 4;
        const int gc = ((lane & 15) & 8) | (((lane & 15) & 7) ^ (vr & 7));
        vg[j] = vbase + (size_t)vr * T_LEN + gc * 8;
    }

    {   // stage Q into Ks (dead until first K staging round)
        const int sr = tid >> 3, c8 = tid & 7;
        *(int4*)&Ks[sr][(c8 ^ (sr & 7)) * 8] =
            *(const int4*)(qbase + (size_t)(t0 + sr) * RS + c8 * 8);
        *(int4*)&Ks[sr + 32][(c8 ^ ((sr + 32) & 7)) * 8] =
            *(const int4*)(qbase + (size_t)(t0 + sr + 32) * RS + c8 * 8);
    }
    __syncthreads();
    short8v qf[4][2];
    #pragma unroll
    for (int mb = 0; mb < 4; ++mb)
        #pragma unroll
        for (int ks = 0; ks < 2; ++ks) {
            int row = mb * 16 + r;
            qf[mb][ks] = *(const short8v*)&Ks[row][((ks * 4 + q) ^ (row & 7)) * 8];
        }

    float l_part[4] = {0.f, 0.f, 0.f, 0.f};
    floatx4 o[4][4];
    #pragma unroll
    for (int mb = 0; mb < 4; ++mb)
        #pragma unroll
        for (int nb = 0; nb < 4; ++nb)
            #pragma unroll
            for (int e = 0; e < 4; ++e) o[mb][nb][e] = 0.f;

    // V read position: global 16B-chunk g = t2*8 + w*2 + (q>>1); LDS chunk
    // holding it = (g&8)|((g&7)^(d&7)), d&7 == r&7; +(q&1)*4 shorts for the
    // 8B half. s covered = t2*64 + w*16 + q*4 + j  (j=0..3 within the b64).
    const int voffbase = (((w * 2 + (q >> 1)) ^ (r & 7)) * 8) + (q & 1) * 4;

    const int ntiles = tt + 1;
    int s2 = 0;
    for (; s2 + 2 <= ntiles; s2 += 2) {   // paired rounds: 128 s per stage
        __syncthreads();                  // prior round's Ks/Vt reads done
        {
            const short* kgr = kg + (size_t)(s2 * 64) * RS;
            #pragma unroll
            for (int j = 0; j < 4; ++j)
                async16(kgr + (size_t)(j * 8) * RS, &Ks[w * 32 + j * 8][0]);
            #pragma unroll
            for (int j = 0; j < 4; ++j)
                async16(vg[j] + s2 * 64, &Vt[w * 16 + j * 4][0]);
        }
        __syncthreads();                  // vmcnt(0) drain + barrier
        #pragma unroll
        for (int t2 = 0; t2 < 2; ++t2) {
            const int krow = t2 * 64 + w * 16 + r;
            const int ksw = krow & 7;
            short8v kf0 = *(const short8v*)&Ks[krow][(q ^ ksw) * 8];
            short8v kf1 = *(const short8v*)&Ks[krow][((4 + q) ^ ksw) * 8];
            short4v vf[4];
            #pragma unroll
            for (int nb = 0; nb < 4; ++nb)
                vf[nb] = *(const short4v*)&Vt[nb * 16 + r][t2 * 64 + voffbase];
            const bool diag = (s2 + t2 == tt);
            #pragma unroll
            for (int mb = 0; mb < 4; ++mb) {
                floatx4 sf;
                #pragma unroll
                for (int e = 0; e < 4; ++e) sf[e] = 0.f;
                sf = __builtin_amdgcn_mfma_f32_16x16x32_bf16(kf0, qf[mb][0], sf, 0, 0, 0);
                sf = __builtin_amdgcn_mfma_f32_16x16x32_bf16(kf1, qf[mb][1], sf, 0, 0, 0);
                const int t_in = mb * 16 + r;
                const int s_in = w * 16 + q * 4;
                float p0 = (diag && (s_in + 0 > t_in)) ? 0.f : EXP2F(sf[0]);
                float p1 = (diag && (s_in + 1 > t_in)) ? 0.f : EXP2F(sf[1]);
                float p2 = (diag && (s_in + 2 > t_in)) ? 0.f : EXP2F(sf[2]);
                float p3 = (diag && (s_in + 3 > t_in)) ? 0.f : EXP2F(sf[3]);
                l_part[mb] += (p0 + p1) + (p2 + p3);
                short4v pa = pack_bf16x4(p0, p1, p2, p3);
                #pragma unroll
                for (int nb = 0; nb < 4; ++nb)
                    o[mb][nb] = MFMA16(pa, vf[nb], o[mb][nb]);
            }
        }
    }
    if (s2 < ntiles) {   // odd tail: single tile s2 == tt (diagonal)
        __syncthreads();
        {   // 64 rows x 8 chunks each (2 int4/thread), read-swizzle-matched
            const int sr = tid >> 2, cb = (tid & 3) * 2;
            const short* kp = kbase + (size_t)(s2 * 64 + sr) * RS;
            const short* vp = vbase + (size_t)sr * T_LEN + s2 * 64;
            #pragma unroll
            for (int u = 0; u < 2; ++u) {
                const int c = cb + u;
                *(int4*)&Ks[sr][(c ^ (sr & 7)) * 8] = *(const int4*)(kp + c * 8);
                *(int4*)&Vt[sr][(c ^ (sr & 7)) * 8] = *(const int4*)(vp + c * 8);
            }
        }
        __syncthreads();
        const int krow = w * 16 + r;
        const int ksw = krow & 7;
        short8v kf0 = *(const short8v*)&Ks[krow][(q ^ ksw) * 8];
        short8v kf1 = *(const short8v*)&Ks[krow][((4 + q) ^ ksw) * 8];
        short4v vf[4];
        #pragma unroll
        for (int nb = 0; nb < 4; ++nb)
            vf[nb] = *(const short4v*)&Vt[nb * 16 + r][voffbase];
        #pragma unroll
        for (int mb = 0; mb < 4; ++mb) {
            floatx4 sf;
            #pragma unroll
            for (int e = 0; e < 4; ++e) sf[e] = 0.f;
            sf = __builtin_amdgcn_mfma_f32_16x16x32_bf16(kf0, qf[mb][0], sf, 0, 0, 0);
            sf = __builtin_amdgcn_mfma_f32_16x16x32_bf16(kf1, qf[mb][1], sf, 0, 0, 0);
            const int t_in = mb * 16 + r;
            const int s_in = w * 16 + q * 4;
            float p0 = (s_in + 0 > t_in) ? 0.f : EXP2F(sf[0]);
            float p1 = (s_in + 1 > t_in) ? 0.f : EXP2F(sf[1]);
            float p2 = (s_in + 2 > t_in) ? 0.f : EXP2F(sf[2]);
            float p3 = (s_in + 3 > t_in) ? 0.f : EXP2F(sf[3]);
            l_part[mb] += (p0 + p1) + (p2 + p3);
            short4v pa = pack_bf16x4(p0, p1, p2, p3);
            #pragma unroll
            for (int nb = 0; nb < 4; ++nb)
                o[mb][nb] = MFMA16(pa, vf[nb], o[mb][nb]);
        }
    }

    // ---- epilogue 1: l reduction. lane (q,r) holds partial for t=mb*16+r
    // summed over its s-stripe; sum over q (xor 16,32), then cross-wave.
    #pragma unroll
    for (int mb = 0; mb < 4; ++mb) {
        float v = l_part[mb];
        v += __shfl_xor(v, 16);
        v += __shfl_xor(v, 32);
        if (q == 0) Lred[w][mb * 16 + r] = v;
    }
    __syncthreads();
    if (tid < 64) {
        float s = Lred[0][tid] + Lred[1][tid] + Lred[2][tid] + Lred[3][tid];
        Lr[(size_t)bh * T_LEN + t0 + tid] = s;
        Lred[0][tid] = 1.0f / s;
    }
    __syncthreads();

    // ---- epilogue 2: cross-wave O reduction via LDS overlay.
    // Waves 0,1 -> Ks region; waves 2,3 -> Vt region; [2][64][20] f32 each
    // (pad 20 keeps float4 alignment + 2-way banks). 4 rounds (one per nb).
    float* OA = (float*)&Ks[0][0];
    float* OB = (float*)&Vt[0][0];
    float* myO = ((w < 2) ? OA : OB) + (size_t)(w & 1) * (64 * 20);
    const int tr = tid >> 2, d4 = (tid & 3) * 4;
    const float inv = Lred[0][tr];
    short* cbase = ctx + ((size_t)(t0 + tr) * BSZ + b) * EMB + h * HDIM + d4;
    #pragma unroll
    for (int nb = 0; nb < 4; ++nb) {
        #pragma unroll
        for (int mb = 0; mb < 4; ++mb)
            #pragma unroll
            for (int i = 0; i < 4; ++i)
                myO[(mb * 16 + q * 4 + i) * 20 + r] = o[mb][nb][i];
        __syncthreads();
        float4 va = *(float4*)&OA[tr * 20 + d4];
        float4 vb = *(float4*)&OA[64 * 20 + tr * 20 + d4];
        float4 vc = *(float4*)&OB[tr * 20 + d4];
        float4 vd = *(float4*)&OB[64 * 20 + tr * 20 + d4];
        float v0 = (va.x + vb.x + vc.x + vd.x) * inv;
        float v1 = (va.y + vb.y + vc.y + vd.y) * inv;
        float v2 = (va.z + vb.z + vc.z + vd.z) * inv;
        float v3 = (va.w + vb.w + vc.w + vd.w) * inv;
        short4 pk = make_short4(f2bf(v0), f2bf(v1), f2bf(v2), f2bf(v3));
        *(short4*)(cbase + nb * 16) = pk;
        if (nb < 3) __syncthreads();
    }
}

// ---------------------------------------------------------------------------
// avg_w[b,t,s] = (1/H) sum_h exp2(qk') / l_h[t]  (scores pre-scaled by
// log2e in the GEMM). 64x64 output tiles, 2 heads per staging round,
// staging via global_load_lds width 16 (verified R4).
// ---------------------------------------------------------------------------
__global__ __launch_bounds__(256) void avg_w_k(const short* __restrict__ qk,
        const float* __restrict__ Lr, float* __restrict__ avg) {
    const int s0 = blockIdx.x * 64, t0 = blockIdx.y * 64, b = blockIdx.z;
    const int tid = threadIdx.x;
    float* outb = avg + (size_t)b * T_LEN * T_LEN;
    if (s0 > t0) {   // fully masked tile: zero-fill (d_out is poisoned)
        const int ty = tid >> 4, tx = tid & 15;
        const float4 z = make_float4(0.f, 0.f, 0.f, 0.f);
        #pragma unroll
        for (int i = 0; i < 4; ++i)
            *(float4*)&outb[(size_t)(t0 + ty * 4 + i) * T_LEN + s0 + tx * 4] = z;
        return;
    }
    __shared__ short Qs[64][128];
    __shared__ short Ks[64][128];
    __shared__ float Lbuf[NHEAD][64];
    const int lane = tid & 63, w = tid >> 6;
    const int q = lane >> 4, r = lane & 15;
    const short* qbase = qk + (size_t)b * QK_LD;
    const int RS = BSZ * QK_LD;

    // pre-inverted denominators: 16 heads x 64 t-rows (published by drain barrier)
    #pragma unroll
    for (int u = 0; u < 4; ++u) {
        const int li = tid * 4 + u;
        const int h = li >> 6, tl = li & 63;
        Lbuf[h][tl] = 0.0625f / Lr[(size_t)(b * NHEAD + h) * T_LEN + t0 + tl];
    }

    // async staging: wave w stages rows [w*16, w*16+16) of Qs and Ks via
    // 4 issues of 4 rows; global source chunk = (c&8)|((c&7)^(row&7)).
    const short* qg[4]; const short* kg[4];
    #pragma unroll
    for (int j = 0; j < 4; ++j) {
        const int row = w * 16 + j * 4 + (lane >> 4);
        const int c = lane & 15;
        const int gc = (c & 8) | ((c & 7) ^ (row & 7));
        qg[j] = qbase + (size_t)(t0 + row) * RS + gc * 8;
        kg[j] = qbase + EMB + (size_t)(s0 + row) * RS + gc * 8;
    }

    floatx4 acc[4];
    #pragma unroll
    for (int nb = 0; nb < 4; ++nb)
        #pragma unroll
        for (int e = 0; e < 4; ++e) acc[nb][e] = 0.f;

    for (int hp = 0; hp < 8; ++hp) {       // head pairs; hp offset = hp*128 shorts
        __syncthreads();                   // prior round's fragment reads done
        #pragma unroll
        for (int j = 0; j < 4; ++j)
            async16(qg[j] + hp * 128, &Qs[w * 16 + j * 4][0]);
        #pragma unroll
        for (int j = 0; j < 4; ++j)
            async16(kg[j] + hp * 128, &Ks[w * 16 + j * 4][0]);
        __syncthreads();                   // vmcnt(0) drain + barrier

        #pragma unroll
        for (int hs = 0; hs < 2; ++hs) {
            const int h = hp * 2 + hs;
            floatx4 sf[4];
            #pragma unroll
            for (int nb = 0; nb < 4; ++nb)
                #pragma unroll
                for (int e = 0; e < 4; ++e) sf[nb][e] = 0.f;
            #pragma unroll
            for (int ks = 0; ks < 2; ++ks) {
                const int qrow = w * 16 + r;
                short8v qfr = *(const short8v*)
                    &Qs[qrow][((hs * 8) | ((ks * 4 + q) ^ (qrow & 7))) * 8];
                #pragma unroll
                for (int nb = 0; nb < 4; ++nb) {
                    const int krow = nb * 16 + r;
                    short8v kfr = *(const short8v*)
                        &Ks[krow][((hs * 8) | ((ks * 4 + q) ^ (krow & 7))) * 8];
                    sf[nb] = __builtin_amdgcn_mfma_f32_16x16x32_bf16(qfr, kfr, sf[nb], 0, 0, 0);
                }
            }
            #pragma unroll
            for (int i = 0; i < 4; ++i) {
                const int tl = w * 16 + q * 4 + i;
                const float inv = Lbuf[h][tl];
                #pragma unroll
                for (int nb = 0; nb < 4; ++nb) {
                    float e = (s0 == t0 && (nb * 16 + r > tl))
                              ? 0.f : EXP2F(sf[nb][i]) * inv;
                    acc[nb][i] += e;
                }
            }
        }
    }

    #pragma unroll
    for (int i = 0; i < 4; ++i) {
        const int t = t0 + w * 16 + q * 4 + i;
        #pragma unroll
        for (int nb = 0; nb < 4; ++nb)
            outb[(size_t)t * T_LEN + s0 + nb * 16 + r] = acc[nb][i];
    }
}

// ---------------------------------------------------------------------------
// Workspace (40.25 MiB, proven-safe layout). query-bf16 ALIASED onto ctxb
// (dead before flash_fwd writes ctx; stream-serial).
// ---------------------------------------------------------------------------
extern "C" void kernel_launch(void* const* d_in, const int* in_sizes, int n_in,
                              void* d_out, int out_size, void* d_ws, size_t ws_size,
                              hipStream_t stream) {
    (void)in_sizes; (void)n_in; (void)out_size; (void)ws_size;
    const float* query = (const float*)d_in[0];
    const float* w_in  = (const float*)d_in[1];
    const float* b_in  = (const float*)d_in[2];
    const float* w_out = (const float*)d_in[3];
    const float* b_out = (const float*)d_in[4];

    float* out = (float*)d_out;                           // [T,B,E] fp32
    float* avg = out + (size_t)T_LEN * BSZ * EMB;         // [B,T,T] fp32

    short* ws     = (short*)d_ws;
    short* wb_in  = ws;                                   // w_in bf16  [3072,1024]  6 MB
    short* wb_out = wb_in  + (size_t)3072 * 1024;         // w_out bf16 [1024,1024]  2 MB
    short* qkb    = wb_out + (size_t)1024 * 1024;         // q,k bf16   [4096,2048] 16 MB
    short* vTb    = qkb    + (size_t)4096 * 2048;         // V^T bf16   [B*E, T]     8 MB
    short* ctxb   = vTb    + (size_t)BSZ * EMB * T_LEN;   // ctx bf16   [4096,1024]  8 MB
    float* Lr     = (float*)(ctxb + (size_t)4096 * 1024); // [B*H, T]              256 KB
    short* qb     = ctxb;                                 // query bf16 alias (dead before flash)

    f32_to_bf16_k<<<4096, 256, 0, stream>>>(query, qb,     4096 * 1024);
    f32_to_bf16_k<<<3072, 256, 0, stream>>>(w_in,  wb_in,  3072 * 1024);
    f32_to_bf16_k<<<1024, 256, 0, stream>>>(w_out, wb_out, 1024 * 1024);

    // QKV projection: q,k -> qkb (q pre-scaled by 0.125*log2e), v -> vTb
    gemm_bf16<<<dim3(32, 24), 256, 0, stream>>>(qb, wb_in, b_in, qkb, vTb,
                                                4096, 3072, 1024, EMB, 1, QK_LD);
    flash_fwd<<<dim3(32, 32), 256, 0, stream>>>(qkb, vTb, ctxb, Lr);
    avg_w_k<<<dim3(32, 32, 2), 256, 0, stream>>>(qkb, Lr, avg);
    gemm_bf16<<<dim3(32, 8), 256, 0, stream>>>(ctxb, wb_out, b_out, out, (short*)0,
                                               4096, 1024, 1024, 0, 0, 1024);
}

// Round 11
// 228.840 us; speedup vs baseline: 1.1124x; 1.0422x over previous
//
#include <hip/hip_runtime.h>

#define T_LEN 2048
#define BSZ 2
#define EMB 1024
#define NHEAD 16
#define HDIM 64
#define QK_LD 2048   // q,k packed [T*B, 2E]

// q-scale folded with log2(e): scores come out pre-multiplied so that
// exp(s) == exp2(s') exactly. 0.18033688 = 64^-0.5 * log2(e).
#define QSCALE_LOG2E 0.18033688011112042f

// Raw hardware exp2: v_exp_f32 IS 2^x (cdna4_isa §3). NOT exp2f (precise
// OCML libcall, ~10 VALU: R8 post-mortem showed it 2x'd avg_w_k).
__device__ __forceinline__ float exp2_hw(float x) {
    float r;
    asm("v_exp_f32 %0, %1" : "=v"(r) : "v"(x));
    return r;
}
#define EXP2F(x) exp2_hw(x)

typedef __attribute__((ext_vector_type(8))) short short8v;   // 8 bf16 (4 VGPRs)
typedef __attribute__((ext_vector_type(4))) short short4v;   // 4 bf16 (2 VGPRs)
typedef __attribute__((ext_vector_type(4))) float floatx4;   // MFMA C/D

__device__ __forceinline__ short f2bf(float f) {
    unsigned u = __float_as_uint(f);
    u += 0x7fffu + ((u >> 16) & 1u);   // RNE
    return (short)(u >> 16);
}

// 4x f32 -> 4x bf16 by truncation (P values are in (0,1]; <=1 ULP bias on
// the PV numerator only -- threshold headroom 3.8x). 1 VALU/value vs 5 RNE.
__device__ __forceinline__ short4v pack_bf16x4(float a, float b, float c, float d) {
    short4v r;
    r[0] = (short)(__float_as_uint(a) >> 16);
    r[1] = (short)(__float_as_uint(b) >> 16);
    r[2] = (short)(__float_as_uint(c) >> 16);
    r[3] = (short)(__float_as_uint(d) >> 16);
    return r;
}

// 16x16x16 bf16 MFMA (K=16): carried-forward instruction on gfx950.
#if __has_builtin(__builtin_amdgcn_mfma_f32_16x16x16bf16_1k)
#define MFMA16(a, b, c) __builtin_amdgcn_mfma_f32_16x16x16bf16_1k(a, b, c, 0, 0, 0)
#else
__device__ __forceinline__ floatx4 mfma16_asm(short4v a, short4v b, floatx4 c) {
    floatx4 d;
    asm("v_mfma_f32_16x16x16_bf16 %0, %1, %2, %3" : "=v"(d) : "v"(a), "v"(b), "v"(c));
    return d;
}
#define MFMA16(a, b, c) mfma16_asm(a, b, c)
#endif

// async global->LDS, 16B per lane; LDS dest is wave-uniform base + lane*16.
__device__ __forceinline__ void async16(const short* g, short* l) {
    __builtin_amdgcn_global_load_lds(
        (const __attribute__((address_space(1))) void*)g,
        (__attribute__((address_space(3))) void*)l, 16, 0, 0);
}

// ---------------------------------------------------------------------------
// Fused f32->bf16 for all three inputs (one launch instead of three).
// Sizes are exact multiples of 1024 floats -> no partial-vector edge.
// ---------------------------------------------------------------------------
__global__ __launch_bounds__(256) void cvt3_k(const float* __restrict__ sa, short* __restrict__ da, int na,
                                              const float* __restrict__ sb, short* __restrict__ db, int nbv,
                                              const float* __restrict__ sc, short* __restrict__ dc) {
    int i = (blockIdx.x * 256 + threadIdx.x) * 4;
    const float* s; short* d;
    if (i < na)            { s = sa; d = da; }
    else if (i < na + nbv) { s = sb; d = db; i -= na; }
    else                   { s = sc; d = dc; i -= na + nbv; }
    float4 v = *(const float4*)(s + i);
    short4 o = make_short4(f2bf(v.x), f2bf(v.y), f2bf(v.z), f2bf(v.w));
    *(short4*)(d + i) = o;
}

// ---------------------------------------------------------------------------
// C = A[M,K]*B[N,K]^T + bias; cols < scale_cols get *QSCALE_LOG2E.
// bf16 MFMA 16x16x32, 128x128 tile, BK=64 (32 MFMA/thread per barrier pair),
// 4 waves. Staging: global_load_lds width 16, [128][64] tile with
// (c ^ (row&7)) swizzle -- byte-identical to flash_fwd's verified Ks
// handling (linear LDS dest + inverse-swizzled global source, rule 21).
// GRID IS (mtile, ntile): linear%8 = mtile%8 (XCD locality).
// If vTout != 0, cols >= 2*EMB are written TRANSPOSED to vT[b][e][t].
// ---------------------------------------------------------------------------
__global__ __launch_bounds__(256) void gemm_bf16(const short* __restrict__ A,
        const short* __restrict__ B, const float* __restrict__ bias,
        void* __restrict__ Cout, short* __restrict__ vTout,
        int M, int N, int K, int scale_cols, int out_bf16, int ldC) {
    __shared__ short As[128][64];
    __shared__ short Bs[128][64];
    const int tid = threadIdx.x;
    const int m0 = blockIdx.x * 128, n0 = blockIdx.y * 128;   // x=mtile (XCD locality)
    const int lane = tid & 63, w = tid >> 6;
    const int q = lane >> 4, r = lane & 15;
    const int wr = w >> 1, wc = w & 1;

    // staging: wave w stages rows w*32 + j*8 + (lane>>3) (j=0..3);
    // source chunk = (lane&7) ^ (row&7), j-invariant since j*8 ≡ 0 mod 8.
    const int srow0 = w * 32 + (lane >> 3);
    const int csrc = (lane & 7) ^ (srow0 & 7);
    const short* gA = A + (size_t)(m0 + srow0) * K + csrc * 8;
    const short* gB = B + (size_t)(n0 + srow0) * K + csrc * 8;

    floatx4 acc[4][4];
    #pragma unroll
    for (int a = 0; a < 4; ++a)
        #pragma unroll
        for (int b2 = 0; b2 < 4; ++b2)
            #pragma unroll
            for (int e = 0; e < 4; ++e) acc[a][b2][e] = 0.f;

    for (int k0 = 0; k0 < K; k0 += 64) {
        __syncthreads();                 // previous iter's ds_reads complete
        #pragma unroll
        for (int j = 0; j < 4; ++j) {
            async16(gA + (size_t)(j * 8) * K + k0, &As[w * 32 + j * 8][0]);
            async16(gB + (size_t)(j * 8) * K + k0, &Bs[w * 32 + j * 8][0]);
        }
        __syncthreads();                 // vmcnt(0) drain + barrier
        #pragma unroll
        for (int ks = 0; ks < 2; ++ks) {
            short8v af[4], bfr[4];
            #pragma unroll
            for (int mb = 0; mb < 4; ++mb) {
                int row = wr * 64 + mb * 16 + r;
                af[mb] = *(const short8v*)&As[row][((ks * 4 + q) ^ (row & 7)) * 8];
            }
            #pragma unroll
            for (int nb = 0; nb < 4; ++nb) {
                int row = wc * 64 + nb * 16 + r;
                bfr[nb] = *(const short8v*)&Bs[row][((ks * 4 + q) ^ (row & 7)) * 8];
            }
            #pragma unroll
            for (int mb = 0; mb < 4; ++mb)
                #pragma unroll
                for (int nb = 0; nb < 4; ++nb)
                    acc[mb][nb] = __builtin_amdgcn_mfma_f32_16x16x32_bf16(af[mb], bfr[nb], acc[mb][nb], 0, 0, 0);
        }
    }

    #pragma unroll
    for (int nb = 0; nb < 4; ++nb) {
        const int col = n0 + wc * 64 + nb * 16 + r;
        const float bi = bias[col];
        const float sc = (col < scale_cols) ? QSCALE_LOG2E : 1.0f;
        if (vTout && col >= 2 * EMB) {
            const int e = col - 2 * EMB;
            #pragma unroll
            for (int mb = 0; mb < 4; ++mb) {
                const int base = m0 + wr * 64 + mb * 16 + q * 4;   // multiple of 4
                float v0 = acc[mb][nb][0] + bi, v1 = acc[mb][nb][1] + bi;
                float v2 = acc[mb][nb][2] + bi, v3 = acc[mb][nb][3] + bi;
                unsigned lo = (unsigned short)f2bf(v0) | ((unsigned)(unsigned short)f2bf(v2) << 16);
                unsigned hi = (unsigned short)f2bf(v1) | ((unsigned)(unsigned short)f2bf(v3) << 16);
                *(unsigned*)&vTout[(size_t)e * T_LEN + (base >> 1)]         = lo;
                *(unsigned*)&vTout[((size_t)EMB + e) * T_LEN + (base >> 1)] = hi;
            }
        } else {
            #pragma unroll
            for (int mb = 0; mb < 4; ++mb)
                #pragma unroll
                for (int i = 0; i < 4; ++i) {
                    const int rowg = m0 + wr * 64 + mb * 16 + q * 4 + i;
                    const float v = (acc[mb][nb][i] + bi) * sc;
                    if (out_bf16) ((short*)Cout)[(size_t)rowg * ldC + col] = f2bf(v);
                    else          ((float*)Cout)[(size_t)rowg * ldC + col] = v;
                }
        }
    }
}

// ---------------------------------------------------------------------------
// Flash causal attention, SWAPPED-QK in-register-P version (R5 structure).
// Scores pre-scaled by log2e (GEMM fold) -> v_exp_f32; P->bf16 by truncation.
// ---------------------------------------------------------------------------
__global__ __launch_bounds__(256) void flash_fwd(const short* __restrict__ qk,
        const short* __restrict__ vT, short* __restrict__ ctx,
        float* __restrict__ Lr) {
    __shared__ __align__(16) short Ks[128][64];   // 2 s-tiles of K; Q pre-loop; O-reduce overlay post-loop
    __shared__ __align__(16) short Vt[64][128];   // V^T [d][2 s-tiles]; O-reduce overlay post-loop
    __shared__ float Lred[4][64];
    const int tid = threadIdx.x;
    const int bh = blockIdx.x;          // XCD locality: linear%8 = bh%8
    const int tt = 31 - blockIdx.y;     // big tiles first
    const int t0 = tt << 6;
    const int b = bh >> 4, h = bh & 15;
    const int lane = tid & 63, w = tid >> 6;
    const int q = lane >> 4, r = lane & 15;
    const int RS = BSZ * QK_LD;

    const short* qbase = qk + (size_t)b * QK_LD + h * HDIM;
    const short* kbase = qbase + EMB;
    const short* vbase = vT + ((size_t)b * EMB + h * HDIM) * T_LEN;

    // async staging geometry (paired rounds), same as verified R4/R5:
    const int krow0 = w * 32 + (lane >> 3);
    const short* kg = kbase + (size_t)krow0 * RS + ((lane & 7) ^ (krow0 & 7)) * 8;
    const int vrow0 = w * 16 + (lane >> 4);
    const short* vg[4];
    #pragma unroll
    for (int j = 0; j < 4; ++j) {
        const int vr = vrow0 + j * 4;
        const int gc = ((lane & 15) & 8) | (((lane & 15) & 7) ^ (vr & 7));
        vg[j] = vbase + (size_t)vr * T_LEN + gc * 8;
    }

    {   // stage Q into Ks (dead until first K staging round)
        const int sr = tid >> 3, c8 = tid & 7;
        *(int4*)&Ks[sr][(c8 ^ (sr & 7)) * 8] =
            *(const int4*)(qbase + (size_t)(t0 + sr) * RS + c8 * 8);
        *(int4*)&Ks[sr + 32][(c8 ^ ((sr + 32) & 7)) * 8] =
            *(const int4*)(qbase + (size_t)(t0 + sr + 32) * RS + c8 * 8);
    }
    __syncthreads();
    short8v qf[4][2];
    #pragma unroll
    for (int mb = 0; mb < 4; ++mb)
        #pragma unroll
        for (int ks = 0; ks < 2; ++ks) {
            int row = mb * 16 + r;
            qf[mb][ks] = *(const short8v*)&Ks[row][((ks * 4 + q) ^ (row & 7)) * 8];
        }

    float l_part[4] = {0.f, 0.f, 0.f, 0.f};
    floatx4 o[4][4];
    #pragma unroll
    for (int mb = 0; mb < 4; ++mb)
        #pragma unroll
        for (int nb = 0; nb < 4; ++nb)
            #pragma unroll
            for (int e = 0; e < 4; ++e) o[mb][nb][e] = 0.f;

    // V read position: global 16B-chunk g = t2*8 + w*2 + (q>>1); LDS chunk
    // holding it = (g&8)|((g&7)^(d&7)), d&7 == r&7; +(q&1)*4 shorts for the
    // 8B half. s covered = t2*64 + w*16 + q*4 + j  (j=0..3 within the b64).
    const int voffbase = (((w * 2 + (q >> 1)) ^ (r & 7)) * 8) + (q & 1) * 4;

    const int ntiles = tt + 1;
    int s2 = 0;
    for (; s2 + 2 <= ntiles; s2 += 2) {   // paired rounds: 128 s per stage
        __syncthreads();                  // prior round's Ks/Vt reads done
        {
            const short* kgr = kg + (size_t)(s2 * 64) * RS;
            #pragma unroll
            for (int j = 0; j < 4; ++j)
                async16(kgr + (size_t)(j * 8) * RS, &Ks[w * 32 + j * 8][0]);
            #pragma unroll
            for (int j = 0; j < 4; ++j)
                async16(vg[j] + s2 * 64, &Vt[w * 16 + j * 4][0]);
        }
        __syncthreads();                  // vmcnt(0) drain + barrier
        #pragma unroll
        for (int t2 = 0; t2 < 2; ++t2) {
            const int krow = t2 * 64 + w * 16 + r;
            const int ksw = krow & 7;
            short8v kf0 = *(const short8v*)&Ks[krow][(q ^ ksw) * 8];
            short8v kf1 = *(const short8v*)&Ks[krow][((4 + q) ^ ksw) * 8];
            short4v vf[4];
            #pragma unroll
            for (int nb = 0; nb < 4; ++nb)
                vf[nb] = *(const short4v*)&Vt[nb * 16 + r][t2 * 64 + voffbase];
            const bool diag = (s2 + t2 == tt);
            #pragma unroll
            for (int mb = 0; mb < 4; ++mb) {
                floatx4 sf;
                #pragma unroll
                for (int e = 0; e < 4; ++e) sf[e] = 0.f;
                sf = __builtin_amdgcn_mfma_f32_16x16x32_bf16(kf0, qf[mb][0], sf, 0, 0, 0);
                sf = __builtin_amdgcn_mfma_f32_16x16x32_bf16(kf1, qf[mb][1], sf, 0, 0, 0);
                const int t_in = mb * 16 + r;
                const int s_in = w * 16 + q * 4;
                float p0 = (diag && (s_in + 0 > t_in)) ? 0.f : EXP2F(sf[0]);
                float p1 = (diag && (s_in + 1 > t_in)) ? 0.f : EXP2F(sf[1]);
                float p2 = (diag && (s_in + 2 > t_in)) ? 0.f : EXP2F(sf[2]);
                float p3 = (diag && (s_in + 3 > t_in)) ? 0.f : EXP2F(sf[3]);
                l_part[mb] += (p0 + p1) + (p2 + p3);
                short4v pa = pack_bf16x4(p0, p1, p2, p3);
                #pragma unroll
                for (int nb = 0; nb < 4; ++nb)
                    o[mb][nb] = MFMA16(pa, vf[nb], o[mb][nb]);
            }
        }
    }
    if (s2 < ntiles) {   // odd tail: single tile s2 == tt (diagonal)
        __syncthreads();
        {   // 64 rows x 8 chunks each (2 int4/thread), read-swizzle-matched
            const int sr = tid >> 2, cb = (tid & 3) * 2;
            const short* kp = kbase + (size_t)(s2 * 64 + sr) * RS;
            const short* vp = vbase + (size_t)sr * T_LEN + s2 * 64;
            #pragma unroll
            for (int u = 0; u < 2; ++u) {
                const int c = cb + u;
                *(int4*)&Ks[sr][(c ^ (sr & 7)) * 8] = *(const int4*)(kp + c * 8);
                *(int4*)&Vt[sr][(c ^ (sr & 7)) * 8] = *(const int4*)(vp + c * 8);
            }
        }
        __syncthreads();
        const int krow = w * 16 + r;
        const int ksw = krow & 7;
        short8v kf0 = *(const short8v*)&Ks[krow][(q ^ ksw) * 8];
        short8v kf1 = *(const short8v*)&Ks[krow][((4 + q) ^ ksw) * 8];
        short4v vf[4];
        #pragma unroll
        for (int nb = 0; nb < 4; ++nb)
            vf[nb] = *(const short4v*)&Vt[nb * 16 + r][voffbase];
        #pragma unroll
        for (int mb = 0; mb < 4; ++mb) {
            floatx4 sf;
            #pragma unroll
            for (int e = 0; e < 4; ++e) sf[e] = 0.f;
            sf = __builtin_amdgcn_mfma_f32_16x16x32_bf16(kf0, qf[mb][0], sf, 0, 0, 0);
            sf = __builtin_amdgcn_mfma_f32_16x16x32_bf16(kf1, qf[mb][1], sf, 0, 0, 0);
            const int t_in = mb * 16 + r;
            const int s_in = w * 16 + q * 4;
            float p0 = (s_in + 0 > t_in) ? 0.f : EXP2F(sf[0]);
            float p1 = (s_in + 1 > t_in) ? 0.f : EXP2F(sf[1]);
            float p2 = (s_in + 2 > t_in) ? 0.f : EXP2F(sf[2]);
            float p3 = (s_in + 3 > t_in) ? 0.f : EXP2F(sf[3]);
            l_part[mb] += (p0 + p1) + (p2 + p3);
            short4v pa = pack_bf16x4(p0, p1, p2, p3);
            #pragma unroll
            for (int nb = 0; nb < 4; ++nb)
                o[mb][nb] = MFMA16(pa, vf[nb], o[mb][nb]);
        }
    }

    // ---- epilogue 1: l reduction. lane (q,r) holds partial for t=mb*16+r
    // summed over its s-stripe; sum over q (xor 16,32), then cross-wave.
    #pragma unroll
    for (int mb = 0; mb < 4; ++mb) {
        float v = l_part[mb];
        v += __shfl_xor(v, 16);
        v += __shfl_xor(v, 32);
        if (q == 0) Lred[w][mb * 16 + r] = v;
    }
    __syncthreads();
    if (tid < 64) {
        float s = Lred[0][tid] + Lred[1][tid] + Lred[2][tid] + Lred[3][tid];
        Lr[(size_t)bh * T_LEN + t0 + tid] = s;
        Lred[0][tid] = 1.0f / s;
    }
    __syncthreads();

    // ---- epilogue 2: cross-wave O reduction via LDS overlay.
    // Waves 0,1 -> Ks region; waves 2,3 -> Vt region; [2][64][20] f32 each
    // (pad 20 keeps float4 alignment + 2-way banks). 4 rounds (one per nb).
    float* OA = (float*)&Ks[0][0];
    float* OB = (float*)&Vt[0][0];
    float* myO = ((w < 2) ? OA : OB) + (size_t)(w & 1) * (64 * 20);
    const int tr = tid >> 2, d4 = (tid & 3) * 4;
    const float inv = Lred[0][tr];
    short* cbase = ctx + ((size_t)(t0 + tr) * BSZ + b) * EMB + h * HDIM + d4;
    #pragma unroll
    for (int nb = 0; nb < 4; ++nb) {
        #pragma unroll
        for (int mb = 0; mb < 4; ++mb)
            #pragma unroll
            for (int i = 0; i < 4; ++i)
                myO[(mb * 16 + q * 4 + i) * 20 + r] = o[mb][nb][i];
        __syncthreads();
        float4 va = *(float4*)&OA[tr * 20 + d4];
        float4 vb = *(float4*)&OA[64 * 20 + tr * 20 + d4];
        float4 vc = *(float4*)&OB[tr * 20 + d4];
        float4 vd = *(float4*)&OB[64 * 20 + tr * 20 + d4];
        float v0 = (va.x + vb.x + vc.x + vd.x) * inv;
        float v1 = (va.y + vb.y + vc.y + vd.y) * inv;
        float v2 = (va.z + vb.z + vc.z + vd.z) * inv;
        float v3 = (va.w + vb.w + vc.w + vd.w) * inv;
        short4 pk = make_short4(f2bf(v0), f2bf(v1), f2bf(v2), f2bf(v3));
        *(short4*)(cbase + nb * 16) = pk;
        if (nb < 3) __syncthreads();
    }
}

// ---------------------------------------------------------------------------
// avg_w[b,t,s] = (1/H) sum_h exp2(qk') / l_h[t]  (scores pre-scaled by
// log2e in the GEMM). 64x64 output tiles, 2 heads per staging round,
// staging via global_load_lds width 16 (verified R4).
// ---------------------------------------------------------------------------
__global__ __launch_bounds__(256) void avg_w_k(const short* __restrict__ qk,
        const float* __restrict__ Lr, float* __restrict__ avg) {
    const int s0 = blockIdx.x * 64, t0 = blockIdx.y * 64, b = blockIdx.z;
    const int tid = threadIdx.x;
    float* outb = avg + (size_t)b * T_LEN * T_LEN;
    if (s0 > t0) {   // fully masked tile: zero-fill (d_out is poisoned)
        const int ty = tid >> 4, tx = tid & 15;
        const float4 z = make_float4(0.f, 0.f, 0.f, 0.f);
        #pragma unroll
        for (int i = 0; i < 4; ++i)
            *(float4*)&outb[(size_t)(t0 + ty * 4 + i) * T_LEN + s0 + tx * 4] = z;
        return;
    }
    __shared__ short Qs[64][128];
    __shared__ short Ks[64][128];
    __shared__ float Lbuf[NHEAD][64];
    const int lane = tid & 63, w = tid >> 6;
    const int q = lane >> 4, r = lane & 15;
    const short* qbase = qk + (size_t)b * QK_LD;
    const int RS = BSZ * QK_LD;

    // pre-inverted denominators: 16 heads x 64 t-rows (published by drain barrier)
    #pragma unroll
    for (int u = 0; u < 4; ++u) {
        const int li = tid * 4 + u;
        const int h = li >> 6, tl = li & 63;
        Lbuf[h][tl] = 0.0625f / Lr[(size_t)(b * NHEAD + h) * T_LEN + t0 + tl];
    }

    // async staging: wave w stages rows [w*16, w*16+16) of Qs and Ks via
    // 4 issues of 4 rows; global source chunk = (c&8)|((c&7)^(row&7)).
    const short* qg[4]; const short* kg[4];
    #pragma unroll
    for (int j = 0; j < 4; ++j) {
        const int row = w * 16 + j * 4 + (lane >> 4);
        const int c = lane & 15;
        const int gc = (c & 8) | ((c & 7) ^ (row & 7));
        qg[j] = qbase + (size_t)(t0 + row) * RS + gc * 8;
        kg[j] = qbase + EMB + (size_t)(s0 + row) * RS + gc * 8;
    }

    floatx4 acc[4];
    #pragma unroll
    for (int nb = 0; nb < 4; ++nb)
        #pragma unroll
        for (int e = 0; e < 4; ++e) acc[nb][e] = 0.f;

    for (int hp = 0; hp < 8; ++hp) {       // head pairs; hp offset = hp*128 shorts
        __syncthreads();                   // prior round's fragment reads done
        #pragma unroll
        for (int j = 0; j < 4; ++j)
            async16(qg[j] + hp * 128, &Qs[w * 16 + j * 4][0]);
        #pragma unroll
        for (int j = 0; j < 4; ++j)
            async16(kg[j] + hp * 128, &Ks[w * 16 + j * 4][0]);
        __syncthreads();                   // vmcnt(0) drain + barrier

        #pragma unroll
        for (int hs = 0; hs < 2; ++hs) {
            const int h = hp * 2 + hs;
            floatx4 sf[4];
            #pragma unroll
            for (int nb = 0; nb < 4; ++nb)
                #pragma unroll
                for (int e = 0; e < 4; ++e) sf[nb][e] = 0.f;
            #pragma unroll
            for (int ks = 0; ks < 2; ++ks) {
                const int qrow = w * 16 + r;
                short8v qfr = *(const short8v*)
                    &Qs[qrow][((hs * 8) | ((ks * 4 + q) ^ (qrow & 7))) * 8];
                #pragma unroll
                for (int nb = 0; nb < 4; ++nb) {
                    const int krow = nb * 16 + r;
                    short8v kfr = *(const short8v*)
                        &Ks[krow][((hs * 8) | ((ks * 4 + q) ^ (krow & 7))) * 8];
                    sf[nb] = __builtin_amdgcn_mfma_f32_16x16x32_bf16(qfr, kfr, sf[nb], 0, 0, 0);
                }
            }
            #pragma unroll
            for (int i = 0; i < 4; ++i) {
                const int tl = w * 16 + q * 4 + i;
                const float inv = Lbuf[h][tl];
                #pragma unroll
                for (int nb = 0; nb < 4; ++nb) {
                    float e = (s0 == t0 && (nb * 16 + r > tl))
                              ? 0.f : EXP2F(sf[nb][i]) * inv;
                    acc[nb][i] += e;
                }
            }
        }
    }

    #pragma unroll
    for (int i = 0; i < 4; ++i) {
        const int t = t0 + w * 16 + q * 4 + i;
        #pragma unroll
        for (int nb = 0; nb < 4; ++nb)
            outb[(size_t)t * T_LEN + s0 + nb * 16 + r] = acc[nb][i];
    }
}

// ---------------------------------------------------------------------------
// Workspace (40.25 MiB, proven-safe layout). query-bf16 ALIASED onto ctxb
// (dead before flash_fwd writes ctx; stream-serial).
// ---------------------------------------------------------------------------
extern "C" void kernel_launch(void* const* d_in, const int* in_sizes, int n_in,
                              void* d_out, int out_size, void* d_ws, size_t ws_size,
                              hipStream_t stream) {
    (void)in_sizes; (void)n_in; (void)out_size; (void)ws_size;
    const float* query = (const float*)d_in[0];
    const float* w_in  = (const float*)d_in[1];
    const float* b_in  = (const float*)d_in[2];
    const float* w_out = (const float*)d_in[3];
    const float* b_out = (const float*)d_in[4];

    float* out = (float*)d_out;                           // [T,B,E] fp32
    float* avg = out + (size_t)T_LEN * BSZ * EMB;         // [B,T,T] fp32

    short* ws     = (short*)d_ws;
    short* wb_in  = ws;                                   // w_in bf16  [3072,1024]  6 MB
    short* wb_out = wb_in  + (size_t)3072 * 1024;         // w_out bf16 [1024,1024]  2 MB
    short* qkb    = wb_out + (size_t)1024 * 1024;         // q,k bf16   [4096,2048] 16 MB
    short* vTb    = qkb    + (size_t)4096 * 2048;         // V^T bf16   [B*E, T]     8 MB
    short* ctxb   = vTb    + (size_t)BSZ * EMB * T_LEN;   // ctx bf16   [4096,1024]  8 MB
    float* Lr     = (float*)(ctxb + (size_t)4096 * 1024); // [B*H, T]              256 KB
    short* qb     = ctxb;                                 // query bf16 alias (dead before flash)

    // fused convert: query(4096*1024) + w_in(3072*1024) + w_out(1024*1024)
    // = 8192*1024 floats = 8192 blocks of 256 threads x 4 elems.
    cvt3_k<<<8192, 256, 0, stream>>>(query, qb, 4096 * 1024,
                                     w_in, wb_in, 3072 * 1024,
                                     w_out, wb_out);

    // QKV projection: q,k -> qkb (q pre-scaled by 0.125*log2e), v -> vTb
    gemm_bf16<<<dim3(32, 24), 256, 0, stream>>>(qb, wb_in, b_in, qkb, vTb,
                                                4096, 3072, 1024, EMB, 1, QK_LD);
    flash_fwd<<<dim3(32, 32), 256, 0, stream>>>(qkb, vTb, ctxb, Lr);
    avg_w_k<<<dim3(32, 32, 2), 256, 0, stream>>>(qkb, Lr, avg);
    gemm_bf16<<<dim3(32, 8), 256, 0, stream>>>(ctxb, wb_out, b_out, out, (short*)0,
                                               4096, 1024, 1024, 0, 0, 1024);
}